// Round 1
// 779.622 us; speedup vs baseline: 1.2377x; 1.2377x over previous
//
#include <hip/hip_runtime.h>

// LeNet C3 sparse conv: x[32,6,512,512] f32, w[16,6,5,5] f32 (masked by
// connectivity), bias[16] -> out[32,16,508,508] f32, VALID 5x5.
//
// Round 2: move weights out of LDS into SGPRs.
//  - weights are wave-uniform -> repack into d_ws as [ic*5+kh][64] (256B
//    blocks, 50 active floats each), read with uniform indices so the
//    compiler emits s_load_dwordx16 on the scalar pipe (zero VALU/LDS cost)
//  - removes 600 of 660 LDS reads/thread; inner iter = 2x ds_read_b128
//    feeding 200 FMAs
//  - LDS drops 48128 -> 32640 B => 4-5 blocks/CU (was 3); launch_bounds(256,4)
//  - accumulation order unchanged (kh,ic,oc,kw,r) => identical numerics

#define TILE_W 64
#define TILE_H 16
#define IN_W   (TILE_W + 4)   // 68
#define IN_H   (TILE_H + 4)   // 20

// inverse of MAP_S2: for each input channel, the 10 output maps it feeds
#define CONN_TABLE {                              \
    {0, 4, 5, 6, 9, 10, 11, 12, 14, 15},          \
    {0, 1, 5, 6, 7, 10, 11, 12, 13, 15},          \
    {0, 1, 2, 6, 7, 8, 11, 13, 14, 15},           \
    {1, 2, 3, 6, 7, 8, 9, 12, 14, 15},            \
    {2, 3, 4, 7, 8, 9, 10, 12, 13, 15},           \
    {3, 4, 5, 8, 9, 10, 11, 13, 14, 15}}

// ---- tiny repack: wgt[oc][ic][kh][kw] -> rp[(ic*5+kh)*64 + j*5+kw]
__global__ __launch_bounds__(256) void c3_repack(
    const float* __restrict__ wgt, float* __restrict__ rp)
{
    static constexpr int CONN[6][10] = CONN_TABLE;
    for (int idx = threadIdx.x; idx < 6 * 5 * 64; idx += 256) {
        const int blk  = idx >> 6;      // ic*5+kh
        const int slot = idx & 63;
        const int ic = blk / 5, kh = blk % 5;
        float v = 0.f;
        if (slot < 50) {
            const int j = slot / 5, kw = slot % 5;
            const int oc = CONN[ic][j];
            v = wgt[((oc * 6 + ic) * 5 + kh) * 5 + kw];
        }
        rp[idx] = v;
    }
}

template <bool PACKED>
__global__ __launch_bounds__(256, 4) void c3_kernel(
    const float* __restrict__ x, const float* __restrict__ wsrc,
    const float* __restrict__ bias, float* __restrict__ out)
{
    constexpr int IC = 6, OC = 16, H = 512, W = 512, OH = 508, OW = 508;
    static constexpr int CONN[6][10] = CONN_TABLE;

    __shared__ __align__(16) float xs[IC][IN_H][IN_W];   // 32640 B

    const int tid = threadIdx.x;
    const int ow0 = blockIdx.x * TILE_W;
    const int oh0 = blockIdx.y * TILE_H;
    const int n   = blockIdx.z;

    // ---- stage input halo tile (float4 loads, clamp rows, zero OOB cols)
    const float* xn = x + (size_t)n * IC * H * W;
    for (int i = tid; i < IC * IN_H * (IN_W / 4); i += 256) {
        const int ic  = i / (IN_H * 17);
        const int rem = i % (IN_H * 17);
        const int r   = rem / 17;
        const int c4  = (rem % 17) * 4;
        int h = oh0 + r; if (h > H - 1) h = H - 1;   // clamped rows only feed discarded outputs
        const int wc = ow0 + c4;
        float4 v;
        if (wc <= W - 4) {
            v = *(const float4*)(xn + ((size_t)ic * H + h) * W + wc);
        } else {
            v = make_float4(0.f, 0.f, 0.f, 0.f);
        }
        *(float4*)&xs[ic][r][c4] = v;
    }
    __syncthreads();

    // ---- compute: thread -> (row, 4-col group), all 16 oc
    const int row = tid >> 4;        // 0..15
    const int c0  = (tid & 15) * 4;  // 0..60

    float acc[OC][4];
    #pragma unroll
    for (int oc = 0; oc < OC; ++oc)
        #pragma unroll
        for (int r = 0; r < 4; ++r) acc[oc][r] = 0.f;

    #pragma unroll 1
    for (int kh = 0; kh < 5; ++kh) {
        #pragma unroll
        for (int ic = 0; ic < IC; ++ic) {
            float in[8];
            *(float4*)&in[0] = *(const float4*)&xs[ic][row + kh][c0];
            *(float4*)&in[4] = *(const float4*)&xs[ic][row + kh][c0 + 4];
            #pragma unroll
            for (int j = 0; j < 10; ++j) {
                const int oc = CONN[ic][j];
                #pragma unroll
                for (int kw = 0; kw < 5; ++kw) {
                    // uniform address -> scalar load (s_load), SGPR operand in fma
                    const float wv = PACKED
                        ? wsrc[(ic * 5 + kh) * 64 + j * 5 + kw]
                        : wsrc[((oc * 6 + ic) * 5 + kh) * 5 + kw];
                    #pragma unroll
                    for (int r = 0; r < 4; ++r)
                        acc[oc][r] = fmaf(in[r + kw], wv, acc[oc][r]);
                }
            }
        }
    }

    // ---- store (+bias), float4 per oc
    const int oh = oh0 + row;
    const int ow = ow0 + c0;
    if (oh < OH && ow < OW) {
        float* op = out + (((size_t)n * OC) * OH + oh) * OW + ow;
        #pragma unroll
        for (int oc = 0; oc < OC; ++oc) {
            const float b = bias[oc];
            float4 v = make_float4(acc[oc][0] + b, acc[oc][1] + b,
                                   acc[oc][2] + b, acc[oc][3] + b);
            *(float4*)(op + (size_t)oc * OH * OW) = v;
        }
    }
}

extern "C" void kernel_launch(void* const* d_in, const int* in_sizes, int n_in,
                              void* d_out, int out_size, void* d_ws, size_t ws_size,
                              hipStream_t stream) {
    const float* x    = (const float*)d_in[0];
    const float* wgt  = (const float*)d_in[1];
    const float* bias = (const float*)d_in[2];
    float* out = (float*)d_out;
    dim3 grid((508 + TILE_W - 1) / TILE_W,   // 8
              (508 + TILE_H - 1) / TILE_H,   // 32
              32);
    if (ws_size >= 6 * 5 * 64 * sizeof(float)) {
        c3_repack<<<dim3(1), dim3(256), 0, stream>>>(wgt, (float*)d_ws);
        c3_kernel<true><<<grid, dim3(256), 0, stream>>>(
            x, (const float*)d_ws, bias, out);
    } else {
        // workspace too small: read weights directly (still uniform s_loads)
        c3_kernel<false><<<grid, dim3(256), 0, stream>>>(x, wgt, bias, out);
    }
}